// Round 11
// baseline (344.903 us; speedup 1.0000x reference)
//
#include <hip/hip_runtime.h>

typedef float f32x4 __attribute__((ext_vector_type(4)));
typedef short s16x8 __attribute__((ext_vector_type(8)));
typedef unsigned short u16;
typedef u16 u16x4 __attribute__((ext_vector_type(4)));

#define SEQ 2048
#define BATCH 2
#define NH 16
#define DH 128
#define DM 2048
#define MROWS (BATCH * SEQ)  // 4096

// 1/sqrt(128) * log2(e)  (softmax done in exp2 domain)
__device__ constexpr float SCALE2 = 0.12751879523531f;

__device__ __forceinline__ u16 f2bf(float f) {
  unsigned u = __float_as_uint(f);
  u += 0x7fffu + ((u >> 16) & 1u);
  return (u16)(u >> 16);
}
__device__ __forceinline__ float bf2f(u16 b) {
  return __uint_as_float(((unsigned)b) << 16);
}

__device__ __forceinline__ void gld_lds16(const void* g, void* l) {
  __builtin_amdgcn_global_load_lds(
      (const __attribute__((address_space(1))) unsigned int*)g,
      (__attribute__((address_space(3))) unsigned int*)l, 16, 0, 0);
}

// ---------------- fused cast f32 -> bf16 (x, Wq|Wk|Wv concat, Wo) ----------
__global__ __launch_bounds__(256) void cast_all(const float* __restrict__ x,
                                                const float* __restrict__ Wq,
                                                const float* __restrict__ Wk,
                                                const float* __restrict__ Wv,
                                                const float* __restrict__ Wo,
                                                u16* __restrict__ xb,
                                                u16* __restrict__ Wqkvb,
                                                u16* __restrict__ Wob) {
  long i = (long)blockIdx.x * 256 + threadIdx.x;  // float4-group index
  const float* src;
  u16* dst;
  long off;
  if (i < 2097152)      { src = x;  dst = xb;              off = i; }
  else if (i < 3145728) { src = Wq; dst = Wqkvb;           off = i - 2097152; }
  else if (i < 4194304) { src = Wk; dst = Wqkvb + 4194304; off = i - 3145728; }
  else if (i < 5242880) { src = Wv; dst = Wqkvb + 8388608; off = i - 4194304; }
  else                  { src = Wo; dst = Wob;             off = i - 5242880; }
  float4 v = ((const float4*)src)[off];
  u16x4 o;
  o[0] = f2bf(v.x); o[1] = f2bf(v.y); o[2] = f2bf(v.z); o[3] = f2bf(v.w);
  ((u16x4*)dst)[off] = o;
}

// ---------------- GEMM core (bt form, 128x128, m97 structure) --------------
// kept for the Wo projection (512 wg at 128^2 packs 2/CU).
template <bool F32OUT>
__global__ __launch_bounds__(256) void gemm_bt(const u16* __restrict__ A,
                                               const u16* __restrict__ B,
                                               void* __restrict__ Cv,
                                               int M, int N, int K) {
  __shared__ u16 As[128 * 32];
  __shared__ u16 Bs[128 * 32];
  const int tid = threadIdx.x;
  const int wave = tid >> 6;
  const int lane = tid & 63;
  const int r = lane & 15, g = lane >> 4;

  const int mtiles = M >> 7;
  const int nwg = mtiles * (N >> 7);
  const int cpx = nwg >> 3;
  const int bid = blockIdx.x;
  const int swz = (bid & 7) * cpx + (bid >> 3);
  const int m0 = (swz % mtiles) * 128;
  const int n0 = (swz / mtiles) * 128;

  const int wm = (wave >> 1) * 64;
  const int wn = (wave & 1) * 64;

  f32x4 acc[4][4] = {};

  const int row0 = tid >> 2;
  const int col0 = (tid & 3) * 8;
  const u16* ga0 = A + (long)(m0 + row0) * K + col0;
  const u16* ga1 = A + (long)(m0 + 64 + row0) * K + col0;
  const u16* gb0 = B + (long)(n0 + row0) * K + col0;
  const u16* gb1 = B + (long)(n0 + 64 + row0) * K + col0;

  u16* lA0 = &As[wave * 512];
  u16* lA1 = &As[2048 + wave * 512];
  u16* lB0 = &Bs[wave * 512];
  u16* lB1 = &Bs[2048 + wave * 512];

  for (int k0 = 0; k0 < K; k0 += 32) {
    gld_lds16(ga0 + k0, lA0);
    gld_lds16(ga1 + k0, lA1);
    gld_lds16(gb0 + k0, lB0);
    gld_lds16(gb1 + k0, lB1);
    __syncthreads();
    s16x8 af[4], bfr[4];
#pragma unroll
    for (int i = 0; i < 4; i++) {
      af[i]  = *(const s16x8*)&As[(wm + i * 16 + r) * 32 + g * 8];
      bfr[i] = *(const s16x8*)&Bs[(wn + i * 16 + r) * 32 + g * 8];
    }
#pragma unroll
    for (int i = 0; i < 4; i++)
#pragma unroll
      for (int j = 0; j < 4; j++)
        acc[i][j] = __builtin_amdgcn_mfma_f32_16x16x32_bf16(af[i], bfr[j], acc[i][j], 0, 0, 0);
    __syncthreads();
  }

  float* Cf = (float*)Cv;
  u16* Cb = (u16*)Cv;
#pragma unroll
  for (int i = 0; i < 4; i++)
#pragma unroll
    for (int j = 0; j < 4; j++) {
      const int row = m0 + wm + i * 16 + g * 4;
      const int col = n0 + wn + j * 16 + r;
#pragma unroll
      for (int q = 0; q < 4; q++) {
        float v = acc[i][j][q];
        if (F32OUT) Cf[(long)(row + q) * N + col] = v;
        else        Cb[(long)(row + q) * N + col] = f2bf(v);
      }
    }
}

// ---------------- QKV GEMM v3: BM=256 x BN=128, kk-split read-ahead --------
// (unchanged from round 9 — verified at 110 us)
__global__ __launch_bounds__(512, 2) void gemm_qkv8(const u16* __restrict__ A,
                                                    const u16* __restrict__ B,
                                                    u16* __restrict__ Qo,
                                                    u16* __restrict__ Ko,
                                                    u16* __restrict__ Vo) {
  __shared__ u16 Alds[2][256 * 64];
  __shared__ u16 Blds[2][128 * 64];
  const int tid = threadIdx.x, wave = tid >> 6, lane = tid & 63;
  const int r = lane & 15, g = lane >> 4;
  const int wm = wave >> 1, wn = wave & 1;
  const int bid = blockIdx.x;
  const int swz = (bid & 7) * 96 + (bid >> 3);  // 768 wg, bijective
  const int m0 = (swz & 15) * 256;
  const int n0 = (swz >> 4) * 128;

  const int lrow = lane >> 3;
  const int csrc = (lane & 7) ^ lrow;

  f32x4 acc[4][4] = {};
  s16x8 aF[2][4], bF[2][4];

#define STAGE_A(TA, MH, BUF) do {                                             \
  _Pragma("unroll") for (int i_ = 0; i_ < 2; ++i_) {                          \
    const int row0_ = (MH) * 128 + i_ * 64 + wave * 8;                        \
    gld_lds16(A + (long)(m0 + row0_ + lrow) * 2048 + (TA) * 64 + csrc * 8,    \
              &Alds[BUF][row0_ * 64]);                                        \
  } } while (0)
#define STAGE_B(TA, NHh, BUF) do {                                            \
    const int row0_ = (NHh) * 64 + wave * 8;                                  \
    gld_lds16(B + (long)(n0 + row0_ + lrow) * 2048 + (TA) * 64 + csrc * 8,    \
              &Blds[BUF][row0_ * 64]);                                        \
  } while (0)

#define READ_K(KK) do {                                                       \
  _Pragma("unroll") for (int mf = 0; mf < 4; ++mf) {                          \
    const int arow = wm * 64 + mf * 16 + r;                                   \
    aF[KK][mf] = *(const s16x8*)&Ab[arow * 64 +                               \
                                    ((((KK) * 4 + g) ^ (arow & 7)) * 8)];     \
  }                                                                           \
  _Pragma("unroll") for (int nf = 0; nf < 4; ++nf) {                          \
    const int brow = wn * 64 + nf * 16 + r;                                   \
    bF[KK][nf] = *(const s16x8*)&Bb[brow * 64 +                               \
                                    ((((KK) * 4 + g) ^ (brow & 7)) * 8)];     \
  } } while (0)

#define MFMA_K(KK) do {                                                       \
  __builtin_amdgcn_s_setprio(1);                                              \
  _Pragma("unroll") for (int mf = 0; mf < 4; ++mf)                            \
    _Pragma("unroll") for (int nf = 0; nf < 4; ++nf)                          \
      acc[mf][nf] = __builtin_amdgcn_mfma_f32_16x16x32_bf16(                  \
          aF[KK][mf], bF[KK][nf], acc[mf][nf], 0, 0, 0);                      \
  __builtin_amdgcn_s_setprio(0);                                              \
} while (0)

  STAGE_A(0, 0, 0); STAGE_B(0, 0, 0); STAGE_A(0, 1, 0); STAGE_B(0, 1, 0);
  STAGE_A(1, 0, 1); STAGE_B(1, 0, 1);
  asm volatile("s_waitcnt vmcnt(3)" ::: "memory");
  __builtin_amdgcn_s_barrier();

  for (int t = 0; t < 32; ++t) {
    const int bt = t & 1, bn = bt ^ 1;
    const u16* Ab = Alds[bt];
    const u16* Bb = Blds[bt];

    READ_K(0);
    __builtin_amdgcn_sched_barrier(0);
    READ_K(1);
    if (t < 31) { STAGE_A(t + 1, 1, bn); STAGE_B(t + 1, 1, bn); }

    asm volatile("s_waitcnt lgkmcnt(8)" ::: "memory");
    __builtin_amdgcn_sched_barrier(0);
    MFMA_K(0);

    asm volatile("s_waitcnt lgkmcnt(0)" ::: "memory");
    __builtin_amdgcn_sched_barrier(0);
    __builtin_amdgcn_s_barrier();

    if (t < 30) { STAGE_A(t + 2, 0, bt); STAGE_B(t + 2, 0, bt); }
    MFMA_K(1);

    if (t < 30)       asm volatile("s_waitcnt vmcnt(3)" ::: "memory");
    else if (t == 30) asm volatile("s_waitcnt vmcnt(0)" ::: "memory");
    __builtin_amdgcn_s_barrier();
  }
#undef MFMA_K
#undef READ_K
#undef STAGE_B
#undef STAGE_A

  u16* Cb = (n0 < 2048) ? Qo : (n0 < 4096 ? Ko : Vo);
  const int nc0 = n0 & 2047;
#pragma unroll
  for (int mi = 0; mi < 4; ++mi)
#pragma unroll
    for (int ni = 0; ni < 4; ++ni)
#pragma unroll
      for (int q = 0; q < 4; ++q)
        Cb[(long)(m0 + wm * 64 + mi * 16 + g * 4 + q) * 2048 +
           nc0 + wn * 64 + ni * 16 + r] = f2bf(acc[mi][ni][q]);
}

// ---------------- RoPE in-place on Qlin & Klin ------------------------------
__global__ __launch_bounds__(256) void rope_kernel(u16* __restrict__ Q, u16* __restrict__ K,
                                                   const float* __restrict__ cosT,
                                                   const float* __restrict__ sinT) {
  int idx = blockIdx.x * 256 + threadIdx.x;  // bits: d:6 h:4 s:11 b:1
  int d = idx & 63;
  int h = (idx >> 6) & 15;
  int s = (idx >> 10) & 2047;
  int b = idx >> 21;
  float c = cosT[s * DH + d];
  float sn = sinT[s * DH + d];
  long base = ((long)(b * SEQ + s)) * DM + h * DH + d;
  float q1 = bf2f(Q[base]), q2 = bf2f(Q[base + 64]);
  Q[base]      = f2bf(q1 * c - q2 * sn);
  Q[base + 64] = f2bf(q2 * c + q1 * sn);
  float k1 = bf2f(K[base]), k2 = bf2f(K[base + 64]);
  K[base]      = f2bf(k1 * c - k2 * sn);
  K[base + 64] = f2bf(k2 * c + k1 * sn);
}

// ---------------- V transpose: Vlin[(b,s)][h*128+d] -> Vt[b,h,d,s] ---------
__global__ __launch_bounds__(256) void transpose_v(const u16* __restrict__ Vlin,
                                                   u16* __restrict__ Vt) {
  __shared__ u16 tile[64][129];
  int t = threadIdx.x;
  int st = blockIdx.x & 31;
  int h = (blockIdx.x >> 5) & 15;
  int b = blockIdx.x >> 9;
  int s0 = st * 64;
  const u16* src = Vlin + ((long)(b * SEQ + s0)) * DM + h * DH;
#pragma unroll
  for (int rr = 0; rr < 4; rr++) {
    int row = rr * 16 + (t >> 4);
    int col = (t & 15) * 8;
    s16x8 v = *(const s16x8*)&src[(long)row * DM + col];
#pragma unroll
    for (int j = 0; j < 8; j++) tile[row][col + j] = (u16)v[j];
  }
  __syncthreads();
  u16* dst = Vt + ((long)(b * NH + h)) * DH * SEQ + s0;
#pragma unroll
  for (int rr = 0; rr < 4; rr++) {
    int d = rr * 32 + (t >> 3);
    int sc = (t & 7) * 8;
    s16x8 o;
#pragma unroll
    for (int j = 0; j < 8; j++) o[j] = (short)tile[sc + j][d];
    *(s16x8*)&dst[(long)d * SEQ + sc] = o;
  }
}

// ---------------- Flash attention v6.1: 3-phase balanced schedule ----------
// Same as v6, with the combine FIXED: merge weights (a1,a2,1/lf) are per-ROW
// (row = q0+r) quantities but oacc rows are q0+g*4+i -> they must be
// redistributed through an LDS bounce (Alds[wave][r] write, [g*4] read),
// exactly like every other epilogue here. v6 applied them per-lane (wrong
// rows) -> absmax 0.317.

template <int NKK>
__device__ __forceinline__ void softmax_sw(
    f32x4 (&s)[NKK], float& mi, float& li,
    u16 (&pl)[16][64], float (&als)[16],
    int qbase, int k0, int kkbase, int r, int g) {
  const int q = qbase + r;
  const bool edge = (k0 + (kkbase + NKK) * 16 - 1) > qbase;
  float v[NKK * 4];
#pragma unroll
  for (int kk = 0; kk < NKK; kk++)
#pragma unroll
    for (int i = 0; i < 4; i++) {
      float x = s[kk][i] * SCALE2;
      if (edge && (k0 + (kkbase + kk) * 16 + g * 4 + i > q)) x = -1e30f;
      v[kk * 4 + i] = x;
    }
  float t[NKK * 4];
#pragma unroll
  for (int i = 0; i < NKK * 4; i++) t[i] = v[i];
#pragma unroll
  for (int w = NKK * 2; w >= 1; w >>= 1)
#pragma unroll
    for (int i = 0; i < w; i++) t[i] = fmaxf(t[i], t[i + w]);
  float mx = t[0];
  mx = fmaxf(mx, __shfl_xor(mx, 16, 64));
  mx = fmaxf(mx, __shfl_xor(mx, 32, 64));
  const float mnew = fmaxf(mi, mx);
  const float a = exp2f(mi - mnew);
  float p[NKK * 4];
#pragma unroll
  for (int i = 0; i < NKK * 4; i++) p[i] = exp2f(v[i] - mnew);
#pragma unroll
  for (int i = 0; i < NKK * 4; i++) t[i] = p[i];
#pragma unroll
  for (int w = NKK * 2; w >= 1; w >>= 1)
#pragma unroll
    for (int i = 0; i < w; i++) t[i] += t[i + w];
  float ps = t[0];
  ps += __shfl_xor(ps, 16, 64);
  ps += __shfl_xor(ps, 32, 64);
  li = li * a + ps;
  mi = mnew;
  const int sw = (r & 7) << 3;
#pragma unroll
  for (int kk = 0; kk < NKK; kk++) {
    u16x4 w;
#pragma unroll
    for (int i = 0; i < 4; i++) w[i] = f2bf(p[kk * 4 + i]);
    *(u16x4*)&pl[r][((kkbase + kk) * 16 + g * 4) ^ sw] = w;
  }
  als[r] = a;
}

__global__ __launch_bounds__(512, 4) void attn_kernel(const u16* __restrict__ Q,
                                                      const u16* __restrict__ K,
                                                      const u16* __restrict__ Vt,
                                                      u16* __restrict__ O) {
  __shared__ __align__(16) u16 Klds[64 * 128];   // 16 KB, source-swizzled
  __shared__ __align__(16) u16 Vlds[128 * 64];   // 16 KB, source-swizzled
  __shared__ u16 Plds[8][16][64];                // 16 KB
  __shared__ float Alds[8][16];                  // 512 B
  __shared__ float MLx[4][64][2];                // 2 KB (combine m,l)

  const int tid = threadIdx.x, wave = tid >> 6, lane = tid & 63;
  const int r = lane & 15, g = lane >> 4;
  const int bh = blockIdx.x & 31;   // XCD pin
  const int jp = blockIdx.x >> 5;   // strip-pair 0..15
  const int h = bh & 15, b = bh >> 4;
  const bool isB = wave >= 4;
  const int w4 = wave & 3;
  const int h2 = wave >> 2;         // k-half in phase 2
  const int q0A = jp * 64 + w4 * 16;
  const int q0B = (31 - jp) * 64 + w4 * 16;
  const int nt = 32 - jp;

  const u16* Qbh = Q + (long)b * SEQ * DM + h * DH;
  const u16* Kbh = K + (long)b * SEQ * DM + h * DH;
  const u16* Vbh = Vt + ((long)(b * NH + h)) * DH * SEQ;
  u16* Obh = O + (long)b * SEQ * DM + h * DH;

  int q0 = isB ? q0B : q0A;
  s16x8 qf[4];
#pragma unroll
  for (int jj = 0; jj < 4; jj++)
    qf[jj] = *(const s16x8*)&Qbh[(long)(q0 + r) * DM + jj * 32 + g * 8];

  f32x4 oacc[8] = {};
  float mi = -1e30f, li = 0.f;

  for (int kt = 0; kt < nt; ++kt) {
    const int k0 = kt * 64;
    __syncthreads();
#pragma unroll
    for (int c = 0; c < 2; ++c) {
      const int s = c * 512 + tid;
      const int krow = s >> 4;
      const int kch = (s & 15) ^ (krow & 7);
      gld_lds16(Kbh + (long)(k0 + krow) * DM + kch * 8,
                &Klds[(c * 512 + wave * 64) * 8]);
      const int vrow = s >> 3;
      const int vch = (s & 7) ^ (vrow & 7);
      gld_lds16(Vbh + (long)vrow * SEQ + k0 + vch * 8,
                &Vlds[(c * 512 + wave * 64) * 8]);
    }
    __syncthreads();

    const int sw = (r & 7) << 3;
    if (kt <= jp) {
      // ---- phase 1: full tile, own strip ----
      f32x4 sacc[4] = {};
#pragma unroll
      for (int kk = 0; kk < 4; kk++)
#pragma unroll
        for (int jj = 0; jj < 4; jj++) {
          s16x8 kf = *(const s16x8*)&Klds[(kk * 16 + r) * 128 +
                                          (((jj * 4 + g) ^ (r & 7)) * 8)];
          sacc[kk] = __builtin_amdgcn_mfma_f32_16x16x32_bf16(kf, qf[jj], sacc[kk], 0, 0, 0);
        }
      softmax_sw<4>(sacc, mi, li, Plds[wave], Alds[wave], q0, k0, 0, r, g);
      f32x4 av = *(const f32x4*)&Alds[wave][g * 4];
#pragma unroll
      for (int f = 0; f < 8; f++)
#pragma unroll
        for (int i = 0; i < 4; i++) oacc[f][i] *= av[i];
#pragma unroll
      for (int kc = 0; kc < 2; kc++) {
        s16x8 pf = *(const s16x8*)&Plds[wave][r][(kc * 32 + g * 8) ^ sw];
#pragma unroll
        for (int f = 0; f < 8; f++) {
          s16x8 vf = *(const s16x8*)&Vlds[(f * 16 + r) * 64 +
                                          (((kc * 4 + g) ^ (r & 7)) * 8)];
          oacc[f] = __builtin_amdgcn_mfma_f32_16x16x32_bf16(pf, vf, oacc[f], 0, 0, 0);
        }
      }
      if (kt == jp && !isB) {
        // strip A complete: write O, switch to strip-B partial
        Alds[wave][r] = 1.f / li;
        f32x4 iv = *(const f32x4*)&Alds[wave][g * 4];
#pragma unroll
        for (int f = 0; f < 8; f++)
#pragma unroll
          for (int i = 0; i < 4; i++)
            Obh[(long)(q0 + g * 4 + i) * DM + f * 16 + r] = f2bf(oacc[f][i] * iv[i]);
        q0 = q0B;
#pragma unroll
        for (int jj = 0; jj < 4; jj++)
          qf[jj] = *(const s16x8*)&Qbh[(long)(q0 + r) * DM + jj * 32 + g * 8];
        mi = -1e30f; li = 0.f;
#pragma unroll
        for (int f = 0; f < 8; f++) oacc[f] = (f32x4){0.f, 0.f, 0.f, 0.f};
      }
    } else {
      // ---- phase 2: half tile (k in [32*h2, 32*h2+32)) of strip B ----
      f32x4 sacc[2] = {};
#pragma unroll
      for (int kkl = 0; kkl < 2; kkl++)
#pragma unroll
        for (int jj = 0; jj < 4; jj++) {
          s16x8 kf = *(const s16x8*)&Klds[((h2 * 2 + kkl) * 16 + r) * 128 +
                                          (((jj * 4 + g) ^ (r & 7)) * 8)];
          sacc[kkl] = __builtin_amdgcn_mfma_f32_16x16x32_bf16(kf, qf[jj], sacc[kkl], 0, 0, 0);
        }
      softmax_sw<2>(sacc, mi, li, Plds[wave], Alds[wave], q0, k0, h2 * 2, r, g);
      f32x4 av = *(const f32x4*)&Alds[wave][g * 4];
#pragma unroll
      for (int f = 0; f < 8; f++)
#pragma unroll
        for (int i = 0; i < 4; i++) oacc[f][i] *= av[i];
      s16x8 pf = *(const s16x8*)&Plds[wave][r][(h2 * 32 + g * 8) ^ sw];
#pragma unroll
      for (int f = 0; f < 8; f++) {
        s16x8 vf = *(const s16x8*)&Vlds[(f * 16 + r) * 64 +
                                        (((h2 * 4 + g) ^ (r & 7)) * 8)];
        oacc[f] = __builtin_amdgcn_mfma_f32_16x16x32_bf16(pf, vf, oacc[f], 0, 0, 0);
      }
    }
  }

  // ---- combine: A-waves post strip-B partials; B-waves merge & write ----
  __syncthreads();  // staging/compute of last tile done; Klds/Vlds now free
  float* xbuf = (w4 < 2) ? ((float*)Klds + w4 * 2048) : ((float*)Vlds + (w4 - 2) * 2048);
  if (!isB) {
    float* dst = xbuf + lane * 32;
#pragma unroll
    for (int f = 0; f < 8; f++) *(f32x4*)(dst + f * 4) = oacc[f];
    MLx[w4][lane][0] = mi;
    MLx[w4][lane][1] = li;
  }
  __syncthreads();
  if (isB) {
    const float* src = xbuf + lane * 32;
    // per-ROW (row = q0 + r) merge scalars...
    const float m2 = MLx[w4][lane][0];
    const float l2 = MLx[w4][lane][1];
    const float m = fmaxf(mi, m2);
    const float a1 = exp2f(mi - m);
    const float a2 = exp2f(m2 - m);
    const float inv = 1.f / (li * a1 + l2 * a2);
    // ...redistributed to the acc layout (rows g*4+i) via LDS bounce.
    // Alds[wave-4] (the A-waves' buffers) are dead after the barrier above.
    Alds[wave][r]     = a1 * inv;
    Alds[wave - 4][r] = a2 * inv;
    f32x4 w1 = *(const f32x4*)&Alds[wave][g * 4];
    f32x4 w2 = *(const f32x4*)&Alds[wave - 4][g * 4];
#pragma unroll
    for (int f = 0; f < 8; f++) {
      f32x4 o2 = *(const f32x4*)(src + f * 4);
#pragma unroll
      for (int i = 0; i < 4; i++)
        oacc[f][i] = oacc[f][i] * w1[i] + o2[i] * w2[i];
    }
#pragma unroll
    for (int f = 0; f < 8; f++)
#pragma unroll
      for (int i = 0; i < 4; i++)
        Obh[(long)(q0 + g * 4 + i) * DM + f * 16 + r] = f2bf(oacc[f][i]);
  }
}

// ---------------- launch ----------------------------------------------------
extern "C" void kernel_launch(void* const* d_in, const int* in_sizes, int n_in,
                              void* d_out, int out_size, void* d_ws, size_t ws_size,
                              hipStream_t stream) {
  const float* x    = (const float*)d_in[0];
  const float* Wq   = (const float*)d_in[1];
  const float* Wk   = (const float*)d_in[2];
  const float* Wv   = (const float*)d_in[3];
  const float* Wo   = (const float*)d_in[4];
  const float* cosT = (const float*)d_in[5];
  const float* sinT = (const float*)d_in[6];
  // d_in[7] = mask: causal, applied analytically.

  if (ws_size < (size_t)134217728) return;  // need 128 MB scratch

  char* ws = (char*)d_ws;
  u16* xb    = (u16*)(ws);               // 16 MB
  u16* Wqkvb = (u16*)(ws + 16777216);    // 24 MB [Wq;Wk;Wv] rows
  u16* Wob   = (u16*)(ws + 41943040);    //  8 MB
  u16* Qlin  = (u16*)(ws + 50331648);    // 16 MB
  u16* Klin  = (u16*)(ws + 67108864);    // 16 MB
  u16* Vlin  = (u16*)(ws + 83886080);    // 16 MB
  u16* Vt    = (u16*)(ws + 100663296);   // 16 MB
  u16* Olin  = (u16*)(ws + 117440512);   // 16 MB

  cast_all<<<24576, 256, 0, stream>>>(x, Wq, Wk, Wv, Wo, xb, Wqkvb, Wob);

  gemm_qkv8<<<768, 512, 0, stream>>>(xb, Wqkvb, Qlin, Klin, Vlin);

  rope_kernel<<<16384, 256, 0, stream>>>(Qlin, Klin, cosT, sinT);
  transpose_v<<<1024, 256, 0, stream>>>(Vlin, Vt);
  attn_kernel<<<512, 512, 0, stream>>>(Qlin, Klin, Vt, Olin);

  gemm_bt<true><<<512, 256, 0, stream>>>(Olin, Wob, d_out, MROWS, DM, DM);
}

// Round 12
// 264.888 us; speedup vs baseline: 1.3021x; 1.3021x over previous
//
#include <hip/hip_runtime.h>

typedef float f32x4 __attribute__((ext_vector_type(4)));
typedef short s16x8 __attribute__((ext_vector_type(8)));
typedef unsigned short u16;
typedef u16 u16x4 __attribute__((ext_vector_type(4)));

#define SEQ 2048
#define BATCH 2
#define NH 16
#define DH 128
#define DM 2048
#define MROWS (BATCH * SEQ)  // 4096

// 1/sqrt(128) * log2(e)  (softmax done in exp2 domain)
__device__ constexpr float SCALE2 = 0.12751879523531f;

__device__ __forceinline__ u16 f2bf(float f) {
  unsigned u = __float_as_uint(f);
  u += 0x7fffu + ((u >> 16) & 1u);
  return (u16)(u >> 16);
}
__device__ __forceinline__ float bf2f(u16 b) {
  return __uint_as_float(((unsigned)b) << 16);
}

__device__ __forceinline__ void gld_lds16(const void* g, void* l) {
  __builtin_amdgcn_global_load_lds(
      (const __attribute__((address_space(1))) unsigned int*)g,
      (__attribute__((address_space(3))) unsigned int*)l, 16, 0, 0);
}

// ---------------- fused cast f32 -> bf16 (x, Wq|Wk|Wv concat, Wo) ----------
__global__ __launch_bounds__(256) void cast_all(const float* __restrict__ x,
                                                const float* __restrict__ Wq,
                                                const float* __restrict__ Wk,
                                                const float* __restrict__ Wv,
                                                const float* __restrict__ Wo,
                                                u16* __restrict__ xb,
                                                u16* __restrict__ Wqkvb,
                                                u16* __restrict__ Wob) {
  long i = (long)blockIdx.x * 256 + threadIdx.x;  // float4-group index
  const float* src;
  u16* dst;
  long off;
  if (i < 2097152)      { src = x;  dst = xb;              off = i; }
  else if (i < 3145728) { src = Wq; dst = Wqkvb;           off = i - 2097152; }
  else if (i < 4194304) { src = Wk; dst = Wqkvb + 4194304; off = i - 3145728; }
  else if (i < 5242880) { src = Wv; dst = Wqkvb + 8388608; off = i - 4194304; }
  else                  { src = Wo; dst = Wob;             off = i - 5242880; }
  float4 v = ((const float4*)src)[off];
  u16x4 o;
  o[0] = f2bf(v.x); o[1] = f2bf(v.y); o[2] = f2bf(v.z); o[3] = f2bf(v.w);
  ((u16x4*)dst)[off] = o;
}

// ============ shared v3 GEMM body: BM=256 x BN=128, kk-split =================
// (verified structure, round 9: 110 us for N=6144 / 3 rounds)

#define GEMM_V3_BODY(A, B, NTILE_SHIFT)                                       \
  __shared__ u16 Alds[2][256 * 64];                                           \
  __shared__ u16 Blds[2][128 * 64];                                           \
  const int tid = threadIdx.x, wave = tid >> 6, lane = tid & 63;              \
  const int r = lane & 15, g = lane >> 4;                                     \
  const int wm = wave >> 1, wn = wave & 1;                                    \
  const int bid = blockIdx.x;                                                 \
  const int swz = (bid & 7) * (gridDim.x >> 3) + (bid >> 3);                  \
  const int m0 = (swz & 15) * 256;                                            \
  const int n0 = (swz >> 4) * 128;                                            \
  const int lrow = lane >> 3;                                                 \
  const int csrc = (lane & 7) ^ lrow;                                         \
  f32x4 acc[4][4] = {};                                                       \
  s16x8 aF[2][4], bF[2][4];                                                   \
  STAGE_A(0, 0, 0); STAGE_B(0, 0, 0); STAGE_A(0, 1, 0); STAGE_B(0, 1, 0);     \
  STAGE_A(1, 0, 1); STAGE_B(1, 0, 1);                                         \
  asm volatile("s_waitcnt vmcnt(3)" ::: "memory");                            \
  __builtin_amdgcn_s_barrier();                                               \
  for (int t = 0; t < 32; ++t) {                                              \
    const int bt = t & 1, bn = bt ^ 1;                                        \
    const u16* Ab = Alds[bt];                                                 \
    const u16* Bb = Blds[bt];                                                 \
    READ_K(0);                                                                \
    __builtin_amdgcn_sched_barrier(0);                                        \
    READ_K(1);                                                                \
    if (t < 31) { STAGE_A(t + 1, 1, bn); STAGE_B(t + 1, 1, bn); }             \
    asm volatile("s_waitcnt lgkmcnt(8)" ::: "memory");                        \
    __builtin_amdgcn_sched_barrier(0);                                        \
    MFMA_K(0);                                                                \
    asm volatile("s_waitcnt lgkmcnt(0)" ::: "memory");                        \
    __builtin_amdgcn_sched_barrier(0);                                        \
    __builtin_amdgcn_s_barrier();                                             \
    if (t < 30) { STAGE_A(t + 2, 0, bt); STAGE_B(t + 2, 0, bt); }             \
    MFMA_K(1);                                                                \
    if (t < 30)       asm volatile("s_waitcnt vmcnt(3)" ::: "memory");        \
    else if (t == 30) asm volatile("s_waitcnt vmcnt(0)" ::: "memory");        \
    __builtin_amdgcn_s_barrier();                                             \
  }

#define STAGE_A(TA, MH, BUF) do {                                             \
  _Pragma("unroll") for (int i_ = 0; i_ < 2; ++i_) {                          \
    const int row0_ = (MH) * 128 + i_ * 64 + wave * 8;                        \
    gld_lds16(A + (long)(m0 + row0_ + lrow) * 2048 + (TA) * 64 + csrc * 8,    \
              &Alds[BUF][row0_ * 64]);                                        \
  } } while (0)
#define STAGE_B(TA, NHh, BUF) do {                                            \
    const int row0_ = (NHh) * 64 + wave * 8;                                  \
    gld_lds16(B + (long)(n0 + row0_ + lrow) * 2048 + (TA) * 64 + csrc * 8,    \
              &Blds[BUF][row0_ * 64]);                                        \
  } while (0)
#define READ_K(KK) do {                                                       \
  _Pragma("unroll") for (int mf = 0; mf < 4; ++mf) {                          \
    const int arow = wm * 64 + mf * 16 + r;                                   \
    aF[KK][mf] = *(const s16x8*)&Ab[arow * 64 +                               \
                                    ((((KK) * 4 + g) ^ (arow & 7)) * 8)];     \
  }                                                                           \
  _Pragma("unroll") for (int nf = 0; nf < 4; ++nf) {                          \
    const int brow = wn * 64 + nf * 16 + r;                                   \
    bF[KK][nf] = *(const s16x8*)&Bb[brow * 64 +                               \
                                    ((((KK) * 4 + g) ^ (brow & 7)) * 8)];     \
  } } while (0)
#define MFMA_K(KK) do {                                                       \
  __builtin_amdgcn_s_setprio(1);                                              \
  _Pragma("unroll") for (int mf = 0; mf < 4; ++mf)                            \
    _Pragma("unroll") for (int nf = 0; nf < 4; ++nf)                          \
      acc[mf][nf] = __builtin_amdgcn_mfma_f32_16x16x32_bf16(                  \
          aF[KK][mf], bF[KK][nf], acc[mf][nf], 0, 0, 0);                      \
  __builtin_amdgcn_s_setprio(0);                                              \
} while (0)

// ---------------- QKV GEMM (grid 768 = 3 exact rounds) ---------------------
__global__ __launch_bounds__(512, 2) void gemm_qkv8(const u16* __restrict__ A,
                                                    const u16* __restrict__ B,
                                                    u16* __restrict__ Qo,
                                                    u16* __restrict__ Ko,
                                                    u16* __restrict__ Vo) {
  GEMM_V3_BODY(A, B, 4)
  u16* Cb = (n0 < 2048) ? Qo : (n0 < 4096 ? Ko : Vo);
  const int nc0 = n0 & 2047;
#pragma unroll
  for (int mi = 0; mi < 4; ++mi)
#pragma unroll
    for (int ni = 0; ni < 4; ++ni)
#pragma unroll
      for (int q = 0; q < 4; ++q)
        Cb[(long)(m0 + wm * 64 + mi * 16 + g * 4 + q) * 2048 +
           nc0 + wn * 64 + ni * 16 + r] = f2bf(acc[mi][ni][q]);
}

// ---------------- Wo GEMM (grid 256 = 1 exact round, f32 out) --------------
__global__ __launch_bounds__(512, 2) void gemm_wo(const u16* __restrict__ A,
                                                  const u16* __restrict__ B,
                                                  float* __restrict__ C) {
  GEMM_V3_BODY(A, B, 4)
#pragma unroll
  for (int mi = 0; mi < 4; ++mi)
#pragma unroll
    for (int ni = 0; ni < 4; ++ni)
#pragma unroll
      for (int q = 0; q < 4; ++q)
        C[(long)(m0 + wm * 64 + mi * 16 + g * 4 + q) * 2048 +
          n0 + wn * 64 + ni * 16 + r] = acc[mi][ni][q];
}

#undef MFMA_K
#undef READ_K
#undef STAGE_B
#undef STAGE_A
#undef GEMM_V3_BODY

// ---------------- RoPE in-place on Qlin & Klin ------------------------------
__global__ __launch_bounds__(256) void rope_kernel(u16* __restrict__ Q, u16* __restrict__ K,
                                                   const float* __restrict__ cosT,
                                                   const float* __restrict__ sinT) {
  int idx = blockIdx.x * 256 + threadIdx.x;  // bits: d:6 h:4 s:11 b:1
  int d = idx & 63;
  int h = (idx >> 6) & 15;
  int s = (idx >> 10) & 2047;
  int b = idx >> 21;
  float c = cosT[s * DH + d];
  float sn = sinT[s * DH + d];
  long base = ((long)(b * SEQ + s)) * DM + h * DH + d;
  float q1 = bf2f(Q[base]), q2 = bf2f(Q[base + 64]);
  Q[base]      = f2bf(q1 * c - q2 * sn);
  Q[base + 64] = f2bf(q2 * c + q1 * sn);
  float k1 = bf2f(K[base]), k2 = bf2f(K[base + 64]);
  K[base]      = f2bf(k1 * c - k2 * sn);
  K[base + 64] = f2bf(k2 * c + k1 * sn);
}

// ---------------- V transpose: Vlin[(b,s)][h*128+d] -> Vt[b,h,d,s] ---------
__global__ __launch_bounds__(256) void transpose_v(const u16* __restrict__ Vlin,
                                                   u16* __restrict__ Vt) {
  __shared__ u16 tile[64][129];
  int t = threadIdx.x;
  int st = blockIdx.x & 31;
  int h = (blockIdx.x >> 5) & 15;
  int b = blockIdx.x >> 9;
  int s0 = st * 64;
  const u16* src = Vlin + ((long)(b * SEQ + s0)) * DM + h * DH;
#pragma unroll
  for (int rr = 0; rr < 4; rr++) {
    int row = rr * 16 + (t >> 4);
    int col = (t & 15) * 8;
    s16x8 v = *(const s16x8*)&src[(long)row * DM + col];
#pragma unroll
    for (int j = 0; j < 8; j++) tile[row][col + j] = (u16)v[j];
  }
  __syncthreads();
  u16* dst = Vt + ((long)(b * NH + h)) * DH * SEQ + s0;
#pragma unroll
  for (int rr = 0; rr < 4; rr++) {
    int d = rr * 32 + (t >> 3);
    int sc = (t & 7) * 8;
    s16x8 o;
#pragma unroll
    for (int j = 0; j < 8; j++) o[j] = (short)tile[sc + j][d];
    *(s16x8*)&dst[(long)d * SEQ + sc] = o;
  }
}

// ---------------- Flash attention v5 (verified 89 us) + jp-complement ------
// Block pairs (bid, bid+256) land on the same CU; complementary jp makes
// per-CU work constant (49 tile-units) instead of 56-2p (makespan 56->49).

__device__ __forceinline__ void softmax_swapped(
    f32x4 (&s)[4], float& mi, float& li,
    u16 (&pl)[16][64], float (&als)[16],
    int qbase, int k0, int r, int g) {
  const int q = qbase + r;
  const bool edge = (k0 + 63) > qbase;
  float v[16];
#pragma unroll
  for (int kk = 0; kk < 4; kk++)
#pragma unroll
    for (int i = 0; i < 4; i++) {
      float x = s[kk][i] * SCALE2;
      if (edge && (k0 + kk * 16 + g * 4 + i > q)) x = -1e30f;
      v[kk * 4 + i] = x;
    }
  float t8[8], t4[4];
#pragma unroll
  for (int j = 0; j < 8; j++) t8[j] = fmaxf(v[2 * j], v[2 * j + 1]);
#pragma unroll
  for (int j = 0; j < 4; j++) t4[j] = fmaxf(t8[2 * j], t8[2 * j + 1]);
  float mx = fmaxf(fmaxf(t4[0], t4[1]), fmaxf(t4[2], t4[3]));
  mx = fmaxf(mx, __shfl_xor(mx, 16, 64));
  mx = fmaxf(mx, __shfl_xor(mx, 32, 64));
  const float mnew = fmaxf(mi, mx);
  const float a = exp2f(mi - mnew);
  float p[16];
#pragma unroll
  for (int j = 0; j < 16; j++) p[j] = exp2f(v[j] - mnew);
  float s8[8], s4[4];
#pragma unroll
  for (int j = 0; j < 8; j++) s8[j] = p[2 * j] + p[2 * j + 1];
#pragma unroll
  for (int j = 0; j < 4; j++) s4[j] = s8[2 * j] + s8[2 * j + 1];
  float ps = (s4[0] + s4[1]) + (s4[2] + s4[3]);
  ps += __shfl_xor(ps, 16, 64);
  ps += __shfl_xor(ps, 32, 64);
  li = li * a + ps;
  mi = mnew;
  const int sw = (r & 7) << 3;
#pragma unroll
  for (int kk = 0; kk < 4; kk++) {
    u16x4 w;
#pragma unroll
    for (int i = 0; i < 4; i++) w[i] = f2bf(p[kk * 4 + i]);
    *(u16x4*)&pl[r][(kk * 16 + g * 4) ^ sw] = w;
  }
  als[r] = a;
}

__global__ __launch_bounds__(512, 4) void attn_kernel(const u16* __restrict__ Q,
                                                      const u16* __restrict__ K,
                                                      const u16* __restrict__ Vt,
                                                      u16* __restrict__ O) {
  __shared__ u16 Klds[64 * 128];   // 16 KB, source-swizzled
  __shared__ u16 Vlds[128 * 64];   // 16 KB, source-swizzled
  __shared__ u16 Plds[8][16][64];  // 16 KB
  __shared__ float Alds[8][16];    // 512 B

  const int tid = threadIdx.x, wave = tid >> 6, lane = tid & 63;
  const int r = lane & 15, g = lane >> 4;
  const int bh = blockIdx.x & 31;   // XCD pin: all blocks of (b,h) on bh%8
  const int jj = blockIdx.x >> 5;   // 0..15
  const int j = (jj < 8) ? jj : 23 - jj;  // complement pairing across rounds
  const int h = bh & 15, b = bh >> 4;
  const bool isB = wave >= 4;
  const int w4 = wave & 3;
  const int strip = isB ? (31 - j) : j;
  const int q0 = strip * 64 + w4 * 16;
  const int nt = 32 - j;            // staged tiles: kt = 0..31-j
  const int lastA = j;              // A-waves compute while kt <= j

  const u16* Qbh = Q + (long)b * SEQ * DM + h * DH;
  const u16* Kbh = K + (long)b * SEQ * DM + h * DH;
  const u16* Vbh = Vt + ((long)(b * NH + h)) * DH * SEQ;

  s16x8 qf[4];
#pragma unroll
  for (int jq = 0; jq < 4; jq++)
    qf[jq] = *(const s16x8*)&Qbh[(long)(q0 + r) * DM + jq * 32 + g * 8];

  f32x4 oacc[8] = {};
  float mi = -1e30f, li = 0.f;

  for (int kt = 0; kt < nt; ++kt) {
    const int k0 = kt * 64;
    __syncthreads();  // previous tile's LDS readers done
    // ---- stage K (64x128) and V^T (128x64) with source-side XOR swizzle ----
#pragma unroll
    for (int c = 0; c < 2; ++c) {
      const int s = c * 512 + tid;
      const int krow = s >> 4;                    // 0..63
      const int kch = (s & 15) ^ (krow & 7);      // 16B chunk within row
      gld_lds16(Kbh + (long)(k0 + krow) * DM + kch * 8,
                &Klds[(c * 512 + wave * 64) * 8]);
      const int vrow = s >> 3;                    // 0..127
      const int vch = (s & 7) ^ (vrow & 7);
      gld_lds16(Vbh + (long)vrow * SEQ + k0 + vch * 8,
                &Vlds[(c * 512 + wave * 64) * 8]);
    }
    __syncthreads();  // vmcnt(0) drained: tile ready

    const bool active = isB || (kt <= lastA);
    if (active) {
      // ---- QK^T (swapped: K as A-operand) ----
      f32x4 sacc[4] = {};
#pragma unroll
      for (int kk = 0; kk < 4; kk++) {
#pragma unroll
        for (int jq = 0; jq < 4; jq++) {
          s16x8 kf = *(const s16x8*)&Klds[(kk * 16 + r) * 128 +
                                          (((jq * 4 + g) ^ (r & 7)) * 8)];
          sacc[kk] = __builtin_amdgcn_mfma_f32_16x16x32_bf16(kf, qf[jq], sacc[kk], 0, 0, 0);
        }
      }
      softmax_swapped(sacc, mi, li, Plds[wave], Alds[wave], q0, k0, r, g);

      f32x4 av = *(const f32x4*)&Alds[wave][g * 4];
#pragma unroll
      for (int f = 0; f < 8; f++)
#pragma unroll
        for (int i = 0; i < 4; i++) oacc[f][i] *= av[i];

      const int sw = (r & 7) << 3;
#pragma unroll
      for (int kc = 0; kc < 2; kc++) {
        s16x8 pf = *(const s16x8*)&Plds[wave][r][(kc * 32 + g * 8) ^ sw];
#pragma unroll
        for (int f = 0; f < 8; f++) {
          s16x8 vf = *(const s16x8*)&Vlds[(f * 16 + r) * 64 +
                                          (((kc * 4 + g) ^ (r & 7)) * 8)];
          oacc[f] = __builtin_amdgcn_mfma_f32_16x16x32_bf16(pf, vf, oacc[f], 0, 0, 0);
        }
      }
    }
  }

  // ---- epilogue: 1/li redistributed via LDS bounce, direct O write ----
  Alds[wave][r] = 1.f / li;
  f32x4 iv = *(const f32x4*)&Alds[wave][g * 4];
  u16* Obh = O + (long)b * SEQ * DM + h * DH;
#pragma unroll
  for (int f = 0; f < 8; f++)
#pragma unroll
    for (int i = 0; i < 4; i++)
      Obh[(long)(q0 + g * 4 + i) * DM + f * 16 + r] = f2bf(oacc[f][i] * iv[i]);
}

// ---------------- launch ----------------------------------------------------
extern "C" void kernel_launch(void* const* d_in, const int* in_sizes, int n_in,
                              void* d_out, int out_size, void* d_ws, size_t ws_size,
                              hipStream_t stream) {
  const float* x    = (const float*)d_in[0];
  const float* Wq   = (const float*)d_in[1];
  const float* Wk   = (const float*)d_in[2];
  const float* Wv   = (const float*)d_in[3];
  const float* Wo   = (const float*)d_in[4];
  const float* cosT = (const float*)d_in[5];
  const float* sinT = (const float*)d_in[6];
  // d_in[7] = mask: causal, applied analytically.

  if (ws_size < (size_t)134217728) return;  // need 128 MB scratch

  char* ws = (char*)d_ws;
  u16* xb    = (u16*)(ws);               // 16 MB
  u16* Wqkvb = (u16*)(ws + 16777216);    // 24 MB [Wq;Wk;Wv] rows
  u16* Wob   = (u16*)(ws + 41943040);    //  8 MB
  u16* Qlin  = (u16*)(ws + 50331648);    // 16 MB
  u16* Klin  = (u16*)(ws + 67108864);    // 16 MB
  u16* Vlin  = (u16*)(ws + 83886080);    // 16 MB
  u16* Vt    = (u16*)(ws + 100663296);   // 16 MB
  u16* Olin  = (u16*)(ws + 117440512);   // 16 MB

  cast_all<<<24576, 256, 0, stream>>>(x, Wq, Wk, Wv, Wo, xb, Wqkvb, Wob);

  gemm_qkv8<<<768, 512, 0, stream>>>(xb, Wqkvb, Qlin, Klin, Vlin);

  rope_kernel<<<16384, 256, 0, stream>>>(Qlin, Klin, cosT, sinT);
  transpose_v<<<1024, 256, 0, stream>>>(Vlin, Vt);
  attn_kernel<<<512, 512, 0, stream>>>(Qlin, Klin, Vt, Olin);

  gemm_wo<<<256, 512, 0, stream>>>(Olin, Wob, (float*)d_out);
}